// Round 12
// baseline (141.753 us; speedup 1.0000x reference)
//
#include <hip/hip_runtime.h>

typedef short short8 __attribute__((ext_vector_type(8)));
typedef float f32x4 __attribute__((ext_vector_type(4)));

#define H 128
#define NB 16           // real batch rows per block (grid*NB == 4096)
#define TSTEPS 64
#define PRED 32
#define XSTRIDE 260     // 64*4 + 4 pad floats -> conflict-free broadcast reads

// R12 = R11 (R7 geometry: 256 blocks x 512 thr, 8 waves x 16 cols, 2-term
// split, MFMA fc head, folded decoder feedback) with two stall cuts:
//  * x staged in LDS once (R7-proven): NO VMEM ops in the step loop, so
//    __syncthreads' implicit s_waitcnt vmcnt(0) drain is free. R10/R11's
//    global x "prefetch" was structurally defeated by that drain each step.
//  * decoder out[] store moved AFTER the barrier (drains a step later, free).
// R11 lesson: 2-term split (drop Al·Whi) is accuracy-free (quantization floor).
// R10 lesson: don't trade TLP for traffic — chain latency dominates.
// R9 lesson: extra barrier domains don't pay; duplicated MFMA costs.
// R8: grid*NB == B. R6: occupancy demands must fit VGPRs.
// R3 lesson: no numerics changes on the recurrence (raw v_exp/v_rcp cost 43x).

static __device__ __forceinline__ unsigned short bf16_rne(float f) {
  unsigned u = __builtin_bit_cast(unsigned, f);
  u += 0x7fffu + ((u >> 16) & 1u);
  return (unsigned short)(u >> 16);
}
static __device__ __forceinline__ float bf16_f(unsigned short s) {
  unsigned u = ((unsigned)s) << 16;
  return __builtin_bit_cast(float, u);
}
// R2's tanh (verified end-to-end). Do NOT swap for raw v_exp/v_rcp.
static __device__ __forceinline__ float tanh_fast(float v) {
  v = fminf(9.0f, fmaxf(-9.0f, v));
  float e = __expf(2.0f * v);
  return __fdividef(e - 1.0f, e + 1.0f);
}

static __device__ __forceinline__ void split_frag(const f32x4& a, const f32x4& b,
                                                  short8& hi, short8& lo) {
  #pragma unroll
  for (int e = 0; e < 4; ++e) {
    unsigned short h1 = bf16_rne(a[e]);
    hi[e] = (short)h1;
    lo[e] = (short)bf16_rne(a[e] - bf16_f(h1));
    unsigned short h2 = bf16_rne(b[e]);
    hi[e + 4] = (short)h2;
    lo[e + 4] = (short)bf16_rne(b[e] - bf16_f(h2));
  }
}

__global__ __launch_bounds__(512, 2) void traj_kernel(
    const float* __restrict__ x,
    const float* __restrict__ eWih, const float* __restrict__ eWhh,
    const float* __restrict__ ebih, const float* __restrict__ ebhh,
    const float* __restrict__ dWih, const float* __restrict__ dWhh,
    const float* __restrict__ dbih, const float* __restrict__ dbhh,
    const float* __restrict__ fcW, const float* __restrict__ fcb,
    float* __restrict__ out)
{
  __shared__ __align__(16) float x_lds[NB * XSTRIDE];   // 16.6 KB
  __shared__ __align__(16) short h_hi0[NB * H];         // 4 KB, XOR-swizzled
  __shared__ __align__(16) short h_hi1[NB * H];         // 4 KB

  const int tid = threadIdx.x;
  const int lane = tid & 63;
  const int w = tid >> 6;          // wave 0..7 -> 16-col tile
  const int l4 = lane >> 4;
  const int ln = lane & 15;
  const int r0 = blockIdx.x * NB;  // 256 blocks x 16 rows = 4096 ✓
  const int jj = w * 16 + ln;      // this lane's hidden column

  // ---- stage x: 16 rows x 192 floats into padded LDS (one-time) ----
  #pragma unroll
  for (int s = 0; s < 6; ++s) {
    int flat = tid + s * 512;      // = r*192 + rem
    int r = flat / 192;
    int rem = flat - r * 192;
    int t = rem / 3;
    int i = rem - t * 3;
    x_lds[r * XSTRIDE + t * 4 + i] = x[(size_t)r0 * 192 + flat];
  }
  // ---- zero h buffer 0 (h0 = 0) ----
  #pragma unroll
  for (int s = 0; s < 4; ++s)
    h_hi0[tid + s * 512] = 0;

  // ---- encoder weights (row jj of eWhh), split hi/lo (both kept for W) ----
  short8 whi[4], wlo[4];
  #pragma unroll
  for (int kt = 0; kt < 4; ++kt) {
    const float* p = eWhh + jj * H + kt * 32 + l4 * 8;
    split_frag(*(const f32x4*)p, *(const f32x4*)(p + 4), whi[kt], wlo[kt]);
  }
  float bias = ebih[jj] + ebhh[jj];
  float wi[3];
  #pragma unroll
  for (int i = 0; i < 3; ++i) wi[i] = eWih[jj * 3 + i];

  // ---- loop-invariant offsets ----
  int roff[4];
  #pragma unroll
  for (int kt = 0; kt < 4; ++kt)
    roff[kt] = ln * H + ((((kt << 2) + l4) ^ ln) << 3);   // swizzled A-frag
  int wo[4], xb[4];
  #pragma unroll
  for (int reg = 0; reg < 4; ++reg) {
    const int r = l4 * 4 + reg;
    wo[reg] = r * H + (((jj >> 3) ^ r) << 3) + (jj & 7);  // swizzled write
    xb[reg] = r * XSTRIDE;
  }

  auto load_frags = [&](const short* __restrict__ hh, short8* ah) {
    #pragma unroll
    for (int kt = 0; kt < 4; ++kt)
      ah[kt] = *(const short8*)&hh[roff[kt]];
  };
  // One RNN step: 2-term split (Ah·Whi + Ah·Wlo), hi-only h state.
  auto rnn_core = [&](const short8* ah, f32x4 acc0, short* __restrict__ wh) {
    f32x4 accb = {0.f, 0.f, 0.f, 0.f};
    #pragma unroll
    for (int kt = 0; kt < 4; ++kt) {   // 2 independent 4-deep MFMA chains
      acc0 = __builtin_amdgcn_mfma_f32_16x16x32_bf16(ah[kt], whi[kt], acc0, 0, 0, 0);
      accb = __builtin_amdgcn_mfma_f32_16x16x32_bf16(ah[kt], wlo[kt], accb, 0, 0, 0);
    }
    #pragma unroll
    for (int reg = 0; reg < 4; ++reg) {
      float v = tanh_fast(acc0[reg] + accb[reg]);
      wh[wo[reg]] = (short)bf16_rne(v);
    }
  };

  __syncthreads();

  // ======================= encoder: 64 steps, unrolled x2, 1 barrier/step ====
  for (int t = 0; t < TSTEPS; t += 2) {
    {
      short8 ah[4];
      load_frags(h_hi0, ah);
      f32x4 a;
      #pragma unroll
      for (int reg = 0; reg < 4; ++reg) {
        const f32x4 xv = *(const f32x4*)&x_lds[xb[reg] + t * 4];
        a[reg] = bias + wi[0] * xv[0] + wi[1] * xv[1] + wi[2] * xv[2];
      }
      rnn_core(ah, a, h_hi1);
      __syncthreads();
    }
    {
      short8 ah[4];
      load_frags(h_hi1, ah);
      f32x4 a;
      #pragma unroll
      for (int reg = 0; reg < 4; ++reg) {
        const f32x4 xv = *(const f32x4*)&x_lds[xb[reg] + (t + 1) * 4];
        a[reg] = bias + wi[0] * xv[0] + wi[1] * xv[1] + wi[2] * xv[2];
      }
      rnn_core(ah, a, h_hi0);
      __syncthreads();
    }
  }
  // h_enc in h_hi0.

  // ======================= decoder setup =======================
  #pragma unroll
  for (int kt = 0; kt < 4; ++kt) {
    const float* p = dWhh + jj * H + kt * 32 + l4 * 8;
    split_frag(*(const f32x4*)p, *(const f32x4*)(p + 4), whi[kt], wlo[kt]);
  }
  bias = dbih[jj] + dbhh[jj];
  #pragma unroll
  for (int i = 0; i < 3; ++i) wi[i] = dWih[jj * 3 + i];

  // fc head as MFMA B-fragments: B[k][n=o] = fcW[o][k], lanes ln>=3 zero.
  short8 fhi[4];
  #pragma unroll
  for (int kt = 0; kt < 4; ++kt) {
    f32x4 a = {0.f, 0.f, 0.f, 0.f}, b = {0.f, 0.f, 0.f, 0.f};
    if (ln < 3) {
      const float* p = fcW + ln * H + kt * 32 + l4 * 8;
      a = *(const f32x4*)p;
      b = *(const f32x4*)(p + 4);
    }
    short8 hi;
    #pragma unroll
    for (int e = 0; e < 4; ++e) {
      hi[e] = (short)bf16_rne(a[e]);
      hi[e + 4] = (short)bf16_rne(b[e]);
    }
    fhi[kt] = hi;
  }
  const float fcbl = (ln < 3) ? fcb[ln] : 0.f;

  // ---- decoder step 0 (raw dWhh + real input x[:, 63, :] from x_lds) ----
  {
    short8 ah[4];
    load_frags(h_hi0, ah);
    f32x4 a;
    #pragma unroll
    for (int reg = 0; reg < 4; ++reg) {
      const f32x4 xv = *(const f32x4*)&x_lds[xb[reg] + 63 * 4];
      a[reg] = bias + wi[0] * xv[0] + wi[1] * xv[1] + wi[2] * xv[2];
    }
    rnn_core(ah, a, h_hi1);
  }
  __syncthreads();

  // ---- fold feedback: W' = dWhh + dWih@fcW ; bias' = bias + dWih@fcb ----
  #pragma unroll
  for (int kt = 0; kt < 4; ++kt) {
    const int kb = kt * 32 + l4 * 8;
    f32x4 a = *(const f32x4*)(dWhh + jj * H + kb);
    f32x4 b = *(const f32x4*)(dWhh + jj * H + kb + 4);
    #pragma unroll
    for (int o = 0; o < 3; ++o) {
      const f32x4 fa = *(const f32x4*)(fcW + o * H + kb);
      const f32x4 fb = *(const f32x4*)(fcW + o * H + kb + 4);
      #pragma unroll
      for (int e = 0; e < 4; ++e) {
        a[e] += wi[o] * fa[e];
        b[e] += wi[o] * fb[e];
      }
    }
    split_frag(a, b, whi[kt], wlo[kt]);
  }
  const float biasp = bias + wi[0] * fcb[0] + wi[1] * fcb[1] + wi[2] * fcb[2];
  const f32x4 accd = {biasp, biasp, biasp, biasp};

  // ======================= decoder steps 1..31: 1 barrier/step =======================
  const short* rdh = h_hi1;
  short* wrh = h_hi0;
  for (int s = 1; s < PRED; ++s) {
    short8 ah[4];
    load_frags(rdh, ah);
    rnn_core(ah, accd, wrh);
    // pred[s-1] = fcW·h[s-1] + fcb via MFMA on one rotating wave (off-path)
    f32x4 p0 = {0.f, 0.f, 0.f, 0.f};
    const bool mywave = (w == (s & 7));
    if (mywave) {
      #pragma unroll
      for (int kt = 0; kt < 4; ++kt)
        p0 = __builtin_amdgcn_mfma_f32_16x16x32_bf16(ah[kt], fhi[kt], p0, 0, 0, 0);
    }
    __syncthreads();
    // store AFTER the barrier: the store's vmcnt drains at the NEXT barrier,
    // by which time it completed — keeps store latency off the step chain.
    if (mywave && ln < 3) {
      #pragma unroll
      for (int reg = 0; reg < 4; ++reg)
        out[((size_t)(r0 + l4 * 4 + reg) * PRED + (s - 1)) * 3 + ln] =
            p0[reg] + fcbl;
    }
    const short* th = rdh; rdh = wrh; wrh = (short*)th;
  }
  // ---- drain: pred[31] from final h ----
  if (w == 0) {
    short8 ah[4];
    load_frags(rdh, ah);
    f32x4 p0 = {0.f, 0.f, 0.f, 0.f};
    #pragma unroll
    for (int kt = 0; kt < 4; ++kt)
      p0 = __builtin_amdgcn_mfma_f32_16x16x32_bf16(ah[kt], fhi[kt], p0, 0, 0, 0);
    if (ln < 3) {
      #pragma unroll
      for (int reg = 0; reg < 4; ++reg)
        out[((size_t)(r0 + l4 * 4 + reg) * PRED + (PRED - 1)) * 3 + ln] =
            p0[reg] + fcbl;
    }
  }
}

extern "C" void kernel_launch(void* const* d_in, const int* in_sizes, int n_in,
                              void* d_out, int out_size, void* d_ws, size_t ws_size,
                              hipStream_t stream) {
  (void)in_sizes; (void)n_in; (void)out_size; (void)d_ws; (void)ws_size;
  const float* x    = (const float*)d_in[0];
  const float* eWih = (const float*)d_in[1];
  const float* eWhh = (const float*)d_in[2];
  const float* ebih = (const float*)d_in[3];
  const float* ebhh = (const float*)d_in[4];
  const float* dWih = (const float*)d_in[5];
  const float* dWhh = (const float*)d_in[6];
  const float* dbih = (const float*)d_in[7];
  const float* dbhh = (const float*)d_in[8];
  const float* fcW  = (const float*)d_in[9];
  const float* fcb  = (const float*)d_in[10];
  float* out = (float*)d_out;
  traj_kernel<<<dim3(256), dim3(512), 0, stream>>>(   // 256*NB(16) = 4096 rows
      x, eWih, eWhh, ebih, ebhh, dWih, dWhh, dbih, dbhh, fcW, fcb, out);
}